// Round 5
// baseline (670.470 us; speedup 1.0000x reference)
//
#include <hip/hip_runtime.h>
#include <hip/hip_bf16.h>
#include <math.h>

typedef __hip_bfloat16 bf16;
typedef __bf16  bf16x8  __attribute__((ext_vector_type(8)));
typedef float   floatx4 __attribute__((ext_vector_type(4)));

static __device__ __forceinline__ float bf2f(bf16 h) { return __bfloat162float(h); }
static __device__ __forceinline__ bf16  f2bf(float f) { return __float2bfloat16(f); }

// ---------------------------------------------------------------------------
// x (f32, 16M elems) -> bf16, vectorized
// ---------------------------------------------------------------------------
__global__ __launch_bounds__(256) void convx_k(const float4* __restrict__ in,
                                               bf16* __restrict__ out)
{
    const int i = blockIdx.x * 256 + threadIdx.x;   // 0 .. 4194303
    const float4 v = in[i];
    bf16* o = out + (size_t)i * 4;
    o[0] = f2bf(v.x); o[1] = f2bf(v.y); o[2] = f2bf(v.z); o[3] = f2bf(v.w);
}

// ---------------------------------------------------------------------------
// Transpose+convert 5x (1024x1024 f32): dst[n][k] = (bf16)src[k][n]
// ---------------------------------------------------------------------------
__global__ __launch_bounds__(256) void trc_k(
    const float* __restrict__ w0, const float* __restrict__ w1,
    const float* __restrict__ w2, const float* __restrict__ w3,
    const float* __restrict__ w4, bf16* __restrict__ dst)
{
    const float* src;
    switch (blockIdx.z) {
        case 0: src = w0; break;
        case 1: src = w1; break;
        case 2: src = w2; break;
        case 3: src = w3; break;
        default: src = w4; break;
    }
    bf16* d = dst + ((size_t)blockIdx.z << 20);
    __shared__ float tile[32][33];
    const int tx = threadIdx.x & 31;
    const int ty = threadIdx.x >> 5;   // 0..7
    const int bx = blockIdx.x * 32, by = blockIdx.y * 32;
#pragma unroll
    for (int j = 0; j < 32; j += 8)
        tile[ty + j][tx] = src[(size_t)(by + ty + j) * 1024 + bx + tx];
    __syncthreads();
#pragma unroll
    for (int j = 0; j < 32; j += 8)
        d[(size_t)(bx + ty + j) * 1024 + by + tx] = f2bf(tile[tx][ty + j]);
}

// ---------------------------------------------------------------------------
// 256x256-tile REGISTER-STAGED double-buffered GEMM.
// C[m][n] = sum_k A[m][k]*Bt[n][k] + bias[n], mode-dependent epilogue.
// A,Bt bf16; M=16384, N=1024, K=1024. 512 threads = 8 waves (2x4); per-wave
// output 128x64 (8x4 fragments of 16x16). BK=64, 16 K-steps.
//
// ROUND-5 FIX (write-side bank conflicts): r4 wrote thread t -> LDS byte
// rbase*128 + slot*16. A 64-elem row is 128 B = one full 32-bank sweep, so
// the row term drops out of the bank index and 8 lanes (one per row) collide
// per slot -> 8-way conflict x 8 ds_write_b128/thread/step (measured 9.24M
// SQ_LDS_BANK_CONFLICT, 188us). Fix = the DMA version's exact recipe in
// reverse: pre-swizzle the GLOBAL source (granule (t&7)^(rbase&7), same 128B
// segment -> coalescing unchanged) and write LDS LINEARLY (byte = t*16 per
// chunk) -> conflict-free by construction. LDS image and the proven 0-conflict
// fragment-read path are byte-identical to rounds 1-4.
//
// Per K-step: {issue 8 int4 loads for t+1} | sched_barrier |
//             {compute tile t: 24 ds_read_b128 + 64 MFMA per wave} |
//             sched_barrier | {8 ds_write_b128 -> buf^1} | __syncthreads.
// RAW/WAR: a wave's reads/writes drain (lgkm) before it passes __syncthreads;
// writes to a buffer occur strictly after the barrier following the last
// reads of that buffer.
//
// LDS image: slot s (16B granule) of row r holds global granule s^(r&7).
// Read slot (kk*4+quad)^(row&7) -> logical granule kk*4+quad. (r1-3-proven.)
//
// modes: 0=tanh->Db  1=sigmoid*(1-auxf[row])->Db  2=plain->Db  3=gelu->Db
//        4=(+auxb residual)->Df (f32)
//        5=dual: blockIdx.y>=4 selects {WinT1->sigmoid->Db2}
// ---------------------------------------------------------------------------
__global__ __launch_bounds__(512, 2) void gemm2r_k(
    const bf16* __restrict__ A, const bf16* __restrict__ Bt,
    const float* __restrict__ bias, const float* __restrict__ auxf,
    const bf16* __restrict__ auxb, bf16* __restrict__ Db,
    bf16* __restrict__ Db2, float* __restrict__ Df, const int mode)
{
    __shared__ alignas(16) bf16 As[2][256 * 64];   // 32 KiB each
    __shared__ alignas(16) bf16 Bs[2][256 * 64];   // total 128 KiB

    const int tid  = threadIdx.x;
    const int wave = tid >> 6;      // 0..7
    const int lane = tid & 63;
    const int quad = lane >> 4;     // 0..3
    const int l16  = lane & 15;
    const int swz  = l16 & 7;       // row-derived XOR key for fragment reads
    const int wm   = wave >> 2;     // wave row (128 rows)
    const int wn   = wave & 3;      // wave col (64 cols)
    const int bm   = blockIdx.x * 256;

    int bn, emode;
    const bf16* Bte = Bt;
    const float* biase = bias;
    bf16* Dbe = Db;
    if (mode == 5) {
        const int mat = blockIdx.y >> 2;          // 0: tanh/Win0, 1: sigmoid/Win1
        bn    = (blockIdx.y & 3) * 256;
        Bte   = Bt + ((size_t)mat << 20);
        biase = bias + (mat << 10);
        Dbe   = mat ? Db2 : Db;
        emode = mat ? 1 : 0;
    } else {
        bn = blockIdx.y * 256;
        emode = mode;
    }

    // staging: thread t -> rows (t>>3)+64i (i=0..3), global granule
    // (t&7)^(row&7) [pre-swizzled, same 128B segment as t&7 -> coalesced];
    // LDS write byte = t*16 + i*8192  [lane-linear -> conflict-free].
    const int grn   = tid & 7;
    const int rbase = tid >> 3;                        // 0..63; rbase&7 == row&7
    const int gsw   = ((grn ^ (rbase & 7)) << 3);      // swizzled global k-offset
    const int wbase = rbase * 64 + grn * 8;            // linear LDS elem offset
    const bf16* gA = A   + (size_t)(bm + rbase) * 1024 + gsw;
    const bf16* gB = Bte + (size_t)(bn + rbase) * 1024 + gsw;

#define GLOAD(rg, gp, kt) do {                                                    \
        _Pragma("unroll")                                                         \
        for (int i_ = 0; i_ < 4; ++i_)                                            \
            rg[i_] = *(const int4*)(gp + (size_t)(i_ * 64) * 1024 + (kt) * 64);   \
    } while (0)
#define SWRITE(rg, lbuf) do {                                                     \
        _Pragma("unroll")                                                         \
        for (int i_ = 0; i_ < 4; ++i_)                                            \
            *(int4*)&lbuf[wbase + i_ * 4096] = rg[i_];                            \
    } while (0)

    floatx4 acc[8][4];
#pragma unroll
    for (int i = 0; i < 8; ++i)
#pragma unroll
        for (int jj = 0; jj < 4; ++jj)
            acc[i][jj] = (floatx4){0.f, 0.f, 0.f, 0.f};

    // compute one BK=64 tile from (cA, cB); fragment path identical to the
    // correctness-proven r1-3 kernel (0 read bank conflicts measured).
#define COMPUTE(cA, cB) do {                                                      \
        _Pragma("unroll")                                                         \
        for (int kk_ = 0; kk_ < 2; ++kk_) {                                       \
            bf16x8 af_[8], bf_[4];                                                \
            _Pragma("unroll")                                                     \
            for (int fm_ = 0; fm_ < 8; ++fm_)                                     \
                af_[fm_] = *(const bf16x8*)&cA[                                   \
                    (wm * 128 + fm_ * 16 + l16) * 64 +                            \
                    (((kk_ * 4 + quad) ^ swz) << 3)];                             \
            _Pragma("unroll")                                                     \
            for (int fn_ = 0; fn_ < 4; ++fn_)                                     \
                bf_[fn_] = *(const bf16x8*)&cB[                                   \
                    (wn * 64 + fn_ * 16 + l16) * 64 +                             \
                    (((kk_ * 4 + quad) ^ swz) << 3)];                             \
            _Pragma("unroll")                                                     \
            for (int fm_ = 0; fm_ < 8; ++fm_)                                     \
                _Pragma("unroll")                                                 \
                for (int fn_ = 0; fn_ < 4; ++fn_)                                 \
                    acc[fm_][fn_] = __builtin_amdgcn_mfma_f32_16x16x32_bf16(      \
                        af_[fm_], bf_[fn_], acc[fm_][fn_], 0, 0, 0);              \
        }                                                                         \
    } while (0)

    int4 ra[4], rb[4];
    // prologue: tile 0 staged (latency exposed once)
    GLOAD(ra, gA, 0); GLOAD(rb, gB, 0);
    SWRITE(ra, As[0]); SWRITE(rb, Bs[0]);
    __syncthreads();

#pragma unroll 2
    for (int kt = 0; kt < 16; ++kt) {
        const int cur = kt & 1;
        if (kt < 15) { GLOAD(ra, gA, kt + 1); GLOAD(rb, gB, kt + 1); }
        __builtin_amdgcn_sched_barrier(0);   // keep loads issued before compute
        COMPUTE(As[cur], Bs[cur]);
        __builtin_amdgcn_sched_barrier(0);   // keep ds_writes after compute
        if (kt < 15) { SWRITE(ra, As[cur ^ 1]); SWRITE(rb, Bs[cur ^ 1]); }
        __syncthreads();
    }

#undef GLOAD
#undef SWRITE
#undef COMPUTE

    // epilogue. C/D layout: col = lane&15, row = quad*4 + reg (m89-verified)
    float bv[4];
#pragma unroll
    for (int fn = 0; fn < 4; ++fn)
        bv[fn] = biase[bn + wn * 64 + fn * 16 + l16];

#pragma unroll
    for (int fm = 0; fm < 8; ++fm) {
#pragma unroll
        for (int r = 0; r < 4; ++r) {
            const int gm = bm + wm * 128 + fm * 16 + quad * 4 + r;
            const size_t rowoff = (size_t)gm << 10;
            float rowmul = 1.f;
            if (emode == 1) rowmul = 1.f - auxf[gm];
#pragma unroll
            for (int fn = 0; fn < 4; ++fn) {
                const int gn = bn + wn * 64 + fn * 16 + l16;
                float val = acc[fm][fn][r] + bv[fn];
                if (emode == 0)      val = tanhf(val);
                else if (emode == 1) val = rowmul / (1.f + expf(-val));
                else if (emode == 3) val = 0.5f * val * (1.f + erff(val * 0.70710678118654752f));
                if (emode == 4) {
                    val += bf2f(auxb[rowoff + gn]);
                    Df[rowoff + gn] = val;
                } else {
                    Dbe[rowoff + gn] = f2bf(val);
                }
            }
        }
    }
}

// ---------------------------------------------------------------------------
// Chunked linear-recurrence scan: h[t] = f[t]*h[t-1] + (1-f[t])*v[t].
// T=4096 split into 64 chunks of 64. 4096 channels (b,d).
// ---------------------------------------------------------------------------
__global__ __launch_bounds__(256) void scan1_k(
    const bf16* __restrict__ v, const bf16* __restrict__ f,
    float* __restrict__ Ac, float* __restrict__ Bc)
{
    const int idx = blockIdx.x * 256 + threadIdx.x;   // 0..262143
    const int ch = idx & 4095;        // b*1024 + d
    const int c  = idx >> 12;         // chunk 0..63
    const int b  = ch >> 10, d = ch & 1023;
    const size_t base = ((size_t)(b * 4096 + c * 64) << 10) + d;
    float a = 1.f, hb = 0.f;
#pragma unroll 8
    for (int i = 0; i < 64; ++i) {
        const size_t o = base + ((size_t)i << 10);
        const float ft = bf2f(f[o]);
        const float vt = bf2f(v[o]);
        hb = fmaf(ft, hb, (1.f - ft) * vt);
        a *= ft;
    }
    Ac[c * 4096 + ch] = a;
    Bc[c * 4096 + ch] = hb;
}

__global__ __launch_bounds__(256) void scanmid_k(
    const float* __restrict__ Ac, const float* __restrict__ Bc,
    const float* __restrict__ hidden, float* __restrict__ Hin)
{
    const int ch = blockIdx.x * 256 + threadIdx.x;    // 0..4095
    float h = hidden[ch];
#pragma unroll 8
    for (int c = 0; c < 64; ++c) {
        Hin[c * 4096 + ch] = h;
        h = fmaf(Ac[c * 4096 + ch], h, Bc[c * 4096 + ch]);
    }
}

__global__ __launch_bounds__(256) void scan2_k(
    const bf16* __restrict__ v, const bf16* __restrict__ f,
    const float* __restrict__ Hin, bf16* __restrict__ hs,
    float* __restrict__ hT)
{
    const int idx = blockIdx.x * 256 + threadIdx.x;
    const int ch = idx & 4095;
    const int c  = idx >> 12;
    const int b  = ch >> 10, d = ch & 1023;
    const size_t base = ((size_t)(b * 4096 + c * 64) << 10) + d;
    float h = Hin[c * 4096 + ch];
#pragma unroll 8
    for (int i = 0; i < 64; ++i) {
        const size_t o = base + ((size_t)i << 10);
        const float ft = bf2f(f[o]);
        const float vt = bf2f(v[o]);
        h = fmaf(ft, h, (1.f - ft) * vt);
        hs[o] = f2bf(h);
    }
    if (c == 63) hT[ch] = h;
}

// ---------------------------------------------------------------------------
// LayerNorm over D=1024 (f32 in-place on d_out), one block per row.
// ---------------------------------------------------------------------------
__global__ __launch_bounds__(256) void ln_k(
    float* __restrict__ s, const float* __restrict__ g,
    const float* __restrict__ b)
{
    const int row = blockIdx.x;
    const int tid = threadIdx.x;
    const size_t off = (size_t)row << 10;
    const float4 xv = ((const float4*)(s + off))[tid];
    float sum = xv.x + xv.y + xv.z + xv.w;
    float sq  = xv.x * xv.x + xv.y * xv.y + xv.z * xv.z + xv.w * xv.w;
#pragma unroll
    for (int o = 32; o > 0; o >>= 1) {
        sum += __shfl_down(sum, o, 64);
        sq  += __shfl_down(sq,  o, 64);
    }
    __shared__ float s1[4], s2[4];
    if ((tid & 63) == 0) { s1[tid >> 6] = sum; s2[tid >> 6] = sq; }
    __syncthreads();
    sum = s1[0] + s1[1] + s1[2] + s1[3];
    sq  = s2[0] + s2[1] + s2[2] + s2[3];
    const float mean = sum * (1.f / 1024.f);
    const float var  = sq * (1.f / 1024.f) - mean * mean;
    const float rstd = rsqrtf(var + 1e-5f);
    const float4 gv = ((const float4*)g)[tid];
    const float4 bv = ((const float4*)b)[tid];
    float4 y;
    y.x = (xv.x - mean) * rstd * gv.x + bv.x;
    y.y = (xv.y - mean) * rstd * gv.y + bv.y;
    y.z = (xv.z - mean) * rstd * gv.z + bv.z;
    y.w = (xv.w - mean) * rstd * gv.w + bv.w;
    ((float4*)(s + off))[tid] = y;
}

// ---------------------------------------------------------------------------
extern "C" void kernel_launch(void* const* d_in, const int* in_sizes, int n_in,
                              void* d_out, int out_size, void* d_ws, size_t ws_size,
                              hipStream_t stream)
{
    const float* x         = (const float*)d_in[0];   // (4,4096,1024)
    const float* hidden    = (const float*)d_in[1];   // (4,1,1024)
    const float* rnn_start = (const float*)d_in[2];   // (4,4096,1)
    const float* Win       = (const float*)d_in[3];   // (2,1024,1024)
    const float* bin_      = (const float*)d_in[4];   // (2,1024)
    const float* Wout      = (const float*)d_in[5];
    const float* bout      = (const float*)d_in[6];
    const float* W1        = (const float*)d_in[7];
    const float* b1        = (const float*)d_in[8];
    const float* W2        = (const float*)d_in[9];
    const float* b2        = (const float*)d_in[10];
    const float* ln_g      = (const float*)d_in[11];
    const float* ln_b      = (const float*)d_in[12];
    float* out = (float*)d_out;                // out(16777216 f32) ++ hidden_new(4096 f32)
    float* hT  = out + (1u << 24);

    // workspace layout
    char* p = (char*)d_ws;
    bf16* Wt    = (bf16*)p;                    p += 5ull * (1u << 20) * sizeof(bf16);
    bf16* slotA = (bf16*)p;                    p += (1ull << 24) * sizeof(bf16);  // xb, later hs
    bf16* slotB = (bf16*)p;                    p += (1ull << 24) * sizeof(bf16);  // v,  later outp
    bf16* slotC = (bf16*)p;                    p += (1ull << 24) * sizeof(bf16);  // f,  later x_
    float* Ac  = (float*)p;                    p += (1ull << 18) * sizeof(float);
    float* Bc  = (float*)p;                    p += (1ull << 18) * sizeof(float);
    float* Hin = (float*)p;                    p += (1ull << 18) * sizeof(float);

    bf16* WoutT = Wt + 2u * (1u << 20);
    bf16* W1T   = Wt + 3u * (1u << 20);
    bf16* W2T   = Wt + 4u * (1u << 20);

    convx_k<<<16384, 256, 0, stream>>>((const float4*)x, slotA);
    trc_k<<<dim3(32, 32, 5), 256, 0, stream>>>(Win, Win + (1u << 20), Wout, W1, W2, Wt);

    // merged dual GEMM: y>=4 -> Win1/sigmoid.  v -> slotB, f -> slotC
    gemm2r_k<<<dim3(64, 8), 512, 0, stream>>>(slotA, Wt, bin_, rnn_start, nullptr,
                                              slotB, slotC, nullptr, 5);

    // chunked scan: hs -> slotA (xb dead), hT -> d_out tail
    scan1_k<<<1024, 256, 0, stream>>>(slotB, slotC, Ac, Bc);
    scanmid_k<<<16, 256, 0, stream>>>(Ac, Bc, hidden, Hin);
    scan2_k<<<1024, 256, 0, stream>>>(slotB, slotC, Hin, slotA, hT);

    // outp = hs@Wout + bout (-> slotB); x_ = gelu(outp@W1+b1) (-> slotC);
    // s = x_@W2 + b2 + outp -> f32 in d_out
    gemm2r_k<<<dim3(64, 4), 512, 0, stream>>>(slotA, WoutT, bout, nullptr, nullptr,
                                              slotB, nullptr, nullptr, 2);
    gemm2r_k<<<dim3(64, 4), 512, 0, stream>>>(slotB, W1T,   b1,   nullptr, nullptr,
                                              slotC, nullptr, nullptr, 3);
    gemm2r_k<<<dim3(64, 4), 512, 0, stream>>>(slotC, W2T,   b2,   nullptr, slotB,
                                              nullptr, nullptr, out, 4);

    ln_k<<<16384, 256, 0, stream>>>(out, ln_g, ln_b);
}

// Round 6
// 665.926 us; speedup vs baseline: 1.0068x; 1.0068x over previous
//
#include <hip/hip_runtime.h>
#include <hip/hip_bf16.h>
#include <math.h>

typedef __hip_bfloat16 bf16;
typedef __bf16  bf16x8  __attribute__((ext_vector_type(8)));
typedef float   floatx4 __attribute__((ext_vector_type(4)));

typedef const __attribute__((address_space(1))) void global_cv_t;
typedef __attribute__((address_space(3))) void       lds_v_t;

static __device__ __forceinline__ float bf2f(bf16 h) { return __bfloat162float(h); }
static __device__ __forceinline__ bf16  f2bf(float f) { return __float2bfloat16(f); }

__device__ __forceinline__ void load_lds16(const void* g, void* l) {
    // async global->LDS, 16B per lane; LDS dest = wave-uniform base + lane*16
    __builtin_amdgcn_global_load_lds((global_cv_t*)g, (lds_v_t*)l, 16, 0, 0);
}

// ---------------------------------------------------------------------------
// x (f32, 16M elems) -> bf16, vectorized
// ---------------------------------------------------------------------------
__global__ __launch_bounds__(256) void convx_k(const float4* __restrict__ in,
                                               bf16* __restrict__ out)
{
    const int i = blockIdx.x * 256 + threadIdx.x;   // 0 .. 4194303
    const float4 v = in[i];
    bf16* o = out + (size_t)i * 4;
    o[0] = f2bf(v.x); o[1] = f2bf(v.y); o[2] = f2bf(v.z); o[3] = f2bf(v.w);
}

// ---------------------------------------------------------------------------
// Transpose+convert 5x (1024x1024 f32): dst[n][k] = (bf16)src[k][n]
// ---------------------------------------------------------------------------
__global__ __launch_bounds__(256) void trc_k(
    const float* __restrict__ w0, const float* __restrict__ w1,
    const float* __restrict__ w2, const float* __restrict__ w3,
    const float* __restrict__ w4, bf16* __restrict__ dst)
{
    const float* src;
    switch (blockIdx.z) {
        case 0: src = w0; break;
        case 1: src = w1; break;
        case 2: src = w2; break;
        case 3: src = w3; break;
        default: src = w4; break;
    }
    bf16* d = dst + ((size_t)blockIdx.z << 20);
    __shared__ float tile[32][33];
    const int tx = threadIdx.x & 31;
    const int ty = threadIdx.x >> 5;   // 0..7
    const int bx = blockIdx.x * 32, by = blockIdx.y * 32;
#pragma unroll
    for (int j = 0; j < 32; j += 8)
        tile[ty + j][tx] = src[(size_t)(by + ty + j) * 1024 + bx + tx];
    __syncthreads();
#pragma unroll
    for (int j = 0; j < 32; j += 8)
        d[(size_t)(bx + ty + j) * 1024 + by + tx] = f2bf(tile[tx][ty + j]);
}

// ---------------------------------------------------------------------------
// 256x256-tile GEMM, A via DMA-staged LDS, B DIRECT from L2 into registers.
// C[m][n] = sum_k A[m][k]*Bt[n][k] + bias[n]; A,Bt bf16; M=16384, N=K=1024.
// 512 threads = 8 waves (2 wave-rows x 4 wave-cols); per-wave output 128x64
// (8x4 fragments of 16x16). BK=64, 16 K-steps, one barrier per step.
//
// ROUND-6 RATIONALE (LDS-BW roofline): with both operands LDS-staged, each
// K-step moves 256 KB/CU through the 128 B/cyc LDS pipe (A read 4-way, B
// 2-way amplified, + writes) -> ~2500-cyc/step floor regardless of schedule.
// B is only 2 MB (L2-resident per XCD; block->XCD = x%8 keeps A-sharing
// blocks on one XCD). So B skips LDS: 8 global_load_dwordx4/wave/step
// straight into registers, double-buffered one step ahead (BA/BB, static
// names per rule on runtime indexing). LDS now carries A only:
// 128 KB reads + 32 KB DMA writes per CU-step. ds_writes eliminated ->
// the r4/r5 9.24M bank-conflict charge (present for ANY ds_write layout,
// bit-identical across two different mappings) vanishes.
//
// All VMEM (A-DMA + B-loads) issues at step-top with a full compute region
// (~1300 cyc) of cover, so the conservative vmcnt/lgkm drain at the
// per-step __syncthreads is harmless by construction — no counted-vmcnt
// inline asm needed (r1-3 showed this toolchain defeats it anyway).
//
// A staging (r1-3 correctness-proven): pre-swizzled per-lane GLOBAL address
// (granule (t&7)^(row&7), same 128B segment -> coalesced), linear DMA dest
// (base+lane*16). LDS image: slot s of row r holds granule s^(r&7); read
// slot (kk*4+quad)^(l16&7) -> 0 read conflicts (measured r1-3).
//
// Hazards: even step computes As[0] while DMA fills As[1]; the step-end
// barrier drains vmcnt (DMA complete) and lgkm (reads complete) in every
// wave, so the odd step may read As[1] and re-stage As[0] safely.
//
// modes: 0=tanh->Db  1=sigmoid*(1-auxf[row])->Db  2=plain->Db  3=gelu->Db
//        4=(+auxb residual)->Df (f32)
//        5=dual: blockIdx.y>=4 selects {WinT1->sigmoid->Db2}
// ---------------------------------------------------------------------------
__global__ __launch_bounds__(512, 2) void gemmA_k(
    const bf16* __restrict__ A, const bf16* __restrict__ Bt,
    const float* __restrict__ bias, const float* __restrict__ auxf,
    const bf16* __restrict__ auxb, bf16* __restrict__ Db,
    bf16* __restrict__ Db2, float* __restrict__ Df, const int mode)
{
    __shared__ alignas(16) bf16 As[2][256 * 64];   // 32 KiB each, 64 KiB total

    const int tid  = threadIdx.x;
    const int wave = tid >> 6;      // 0..7
    const int lane = tid & 63;
    const int quad = lane >> 4;     // 0..3
    const int l16  = lane & 15;
    const int swz  = l16 & 7;       // row-derived XOR key for fragment reads
    const int wm   = wave >> 2;     // wave row (128 rows)
    const int wn   = wave & 3;      // wave col (64 cols)
    const int bm   = blockIdx.x * 256;

    int bn, emode;
    const bf16* Bte = Bt;
    const float* biase = bias;
    bf16* Dbe = Db;
    if (mode == 5) {
        const int mat = blockIdx.y >> 2;          // 0: tanh/Win0, 1: sigmoid/Win1
        bn    = (blockIdx.y & 3) * 256;
        Bte   = Bt + ((size_t)mat << 20);
        biase = bias + (mat << 10);
        Dbe   = mat ? Db2 : Db;
        emode = mat ? 1 : 0;
    } else {
        bn = blockIdx.y * 256;
        emode = mode;
    }

    // ---- A staging (DMA), r1-3-proven addressing -------------------------
    const int srow = tid >> 3;                         // 0..63; srow&7 == row&7
    const int gsw  = (((tid & 7) ^ (srow & 7)) << 3);  // swizzled global k-off
    const bf16* gA = A + (size_t)(bm + srow) * 1024 + gsw;

#define STAGE_A(BUF, KT) do {                                                     \
        load_lds16(gA + (size_t)(KT) * 64,                                        \
                   &As[BUF][(wave * 8) * 64]);                                    \
        load_lds16(gA + (size_t)64 * 1024 + (size_t)(KT) * 64,                    \
                   &As[BUF][(64 + wave * 8) * 64]);                               \
        load_lds16(gA + (size_t)128 * 1024 + (size_t)(KT) * 64,                   \
                   &As[BUF][(128 + wave * 8) * 64]);                              \
        load_lds16(gA + (size_t)192 * 1024 + (size_t)(KT) * 64,                   \
                   &As[BUF][(192 + wave * 8) * 64]);                              \
    } while (0)

    // ---- B direct loads (L2-hot), one K-step register prefetch ----------
    // element [(bn + wn*64 + fn*16 + l16)][kt*64 + (kk*4+quad)*8 + j]
    const bf16* gB = Bte + (size_t)(bn + wn * 64 + l16) * 1024 + quad * 8;

#define LOADB(rg, KT) do {                                                        \
        _Pragma("unroll")                                                         \
        for (int f_ = 0; f_ < 4; ++f_)                                            \
            _Pragma("unroll")                                                     \
            for (int k_ = 0; k_ < 2; ++k_)                                        \
                rg[f_ * 2 + k_] = *(const int4*)(gB + (size_t)(f_ * 16) * 1024    \
                                                 + (KT) * 64 + k_ * 32);          \
    } while (0)

    floatx4 acc[8][4];
#pragma unroll
    for (int i = 0; i < 8; ++i)
#pragma unroll
        for (int jj = 0; jj < 4; ++jj)
            acc[i][jj] = (floatx4){0.f, 0.f, 0.f, 0.f};

    // compute one BK=64 tile: A-frags from LDS (proven 0-conflict path),
    // B-frags from registers.
#define COMPUTE(BUF, rg) do {                                                     \
        _Pragma("unroll")                                                         \
        for (int kk_ = 0; kk_ < 2; ++kk_) {                                       \
            bf16x8 af_[8];                                                        \
            _Pragma("unroll")                                                     \
            for (int fm_ = 0; fm_ < 8; ++fm_)                                     \
                af_[fm_] = *(const bf16x8*)&As[BUF][                              \
                    (wm * 128 + fm_ * 16 + l16) * 64 +                            \
                    (((kk_ * 4 + quad) ^ swz) << 3)];                             \
            _Pragma("unroll")                                                     \
            for (int fm_ = 0; fm_ < 8; ++fm_)                                     \
                _Pragma("unroll")                                                 \
                for (int fn_ = 0; fn_ < 4; ++fn_)                                 \
                    acc[fm_][fn_] = __builtin_amdgcn_mfma_f32_16x16x32_bf16(      \
                        af_[fm_], *(const bf16x8*)&rg[fn_ * 2 + kk_],             \
                        acc[fm_][fn_], 0, 0, 0);                                  \
        }                                                                         \
    } while (0)

    int4 BA[8], BB[8];
    // prologue: B(0) -> BA, A(0) -> As[0]; one-time latency exposure.
    LOADB(BA, 0);
    STAGE_A(0, 0);
    __syncthreads();

#pragma unroll 1
    for (int it = 0; it < 8; ++it) {
        // even step: kt = 2it (As[0], BA); prefetch kt+1 into As[1], BB.
        LOADB(BB, 2 * it + 1);
        STAGE_A(1, 2 * it + 1);
        __builtin_amdgcn_sched_barrier(0);   // loads issue before compute
        COMPUTE(0, BA);
        __syncthreads();
        // odd step: kt = 2it+1 (As[1], BB); prefetch kt+2 into As[0], BA.
        if (it < 7) {
            LOADB(BA, 2 * it + 2);
            STAGE_A(0, 2 * it + 2);
        }
        __builtin_amdgcn_sched_barrier(0);
        COMPUTE(1, BB);
        __syncthreads();
    }

#undef STAGE_A
#undef LOADB
#undef COMPUTE

    // epilogue. C/D layout: col = lane&15, row = quad*4 + reg (m89-verified)
    float bv[4];
#pragma unroll
    for (int fn = 0; fn < 4; ++fn)
        bv[fn] = biase[bn + wn * 64 + fn * 16 + l16];

#pragma unroll
    for (int fm = 0; fm < 8; ++fm) {
#pragma unroll
        for (int r = 0; r < 4; ++r) {
            const int gm = bm + wm * 128 + fm * 16 + quad * 4 + r;
            const size_t rowoff = (size_t)gm << 10;
            float rowmul = 1.f;
            if (emode == 1) rowmul = 1.f - auxf[gm];
#pragma unroll
            for (int fn = 0; fn < 4; ++fn) {
                const int gn = bn + wn * 64 + fn * 16 + l16;
                float val = acc[fm][fn][r] + bv[fn];
                if (emode == 0)      val = tanhf(val);
                else if (emode == 1) val = rowmul / (1.f + expf(-val));
                else if (emode == 3) val = 0.5f * val * (1.f + erff(val * 0.70710678118654752f));
                if (emode == 4) {
                    val += bf2f(auxb[rowoff + gn]);
                    Df[rowoff + gn] = val;
                } else {
                    Dbe[rowoff + gn] = f2bf(val);
                }
            }
        }
    }
}

// ---------------------------------------------------------------------------
// Chunked linear-recurrence scan: h[t] = f[t]*h[t-1] + (1-f[t])*v[t].
// T=4096 split into 64 chunks of 64. 4096 channels (b,d).
// ---------------------------------------------------------------------------
__global__ __launch_bounds__(256) void scan1_k(
    const bf16* __restrict__ v, const bf16* __restrict__ f,
    float* __restrict__ Ac, float* __restrict__ Bc)
{
    const int idx = blockIdx.x * 256 + threadIdx.x;   // 0..262143
    const int ch = idx & 4095;        // b*1024 + d
    const int c  = idx >> 12;         // chunk 0..63
    const int b  = ch >> 10, d = ch & 1023;
    const size_t base = ((size_t)(b * 4096 + c * 64) << 10) + d;
    float a = 1.f, hb = 0.f;
#pragma unroll 8
    for (int i = 0; i < 64; ++i) {
        const size_t o = base + ((size_t)i << 10);
        const float ft = bf2f(f[o]);
        const float vt = bf2f(v[o]);
        hb = fmaf(ft, hb, (1.f - ft) * vt);
        a *= ft;
    }
    Ac[c * 4096 + ch] = a;
    Bc[c * 4096 + ch] = hb;
}

__global__ __launch_bounds__(256) void scanmid_k(
    const float* __restrict__ Ac, const float* __restrict__ Bc,
    const float* __restrict__ hidden, float* __restrict__ Hin)
{
    const int ch = blockIdx.x * 256 + threadIdx.x;    // 0..4095
    float h = hidden[ch];
#pragma unroll 8
    for (int c = 0; c < 64; ++c) {
        Hin[c * 4096 + ch] = h;
        h = fmaf(Ac[c * 4096 + ch], h, Bc[c * 4096 + ch]);
    }
}

__global__ __launch_bounds__(256) void scan2_k(
    const bf16* __restrict__ v, const bf16* __restrict__ f,
    const float* __restrict__ Hin, bf16* __restrict__ hs,
    float* __restrict__ hT)
{
    const int idx = blockIdx.x * 256 + threadIdx.x;
    const int ch = idx & 4095;
    const int c  = idx >> 12;
    const int b  = ch >> 10, d = ch & 1023;
    const size_t base = ((size_t)(b * 4096 + c * 64) << 10) + d;
    float h = Hin[c * 4096 + ch];
#pragma unroll 8
    for (int i = 0; i < 64; ++i) {
        const size_t o = base + ((size_t)i << 10);
        const float ft = bf2f(f[o]);
        const float vt = bf2f(v[o]);
        h = fmaf(ft, h, (1.f - ft) * vt);
        hs[o] = f2bf(h);
    }
    if (c == 63) hT[ch] = h;
}

// ---------------------------------------------------------------------------
// LayerNorm over D=1024 (f32 in-place on d_out), one block per row.
// ---------------------------------------------------------------------------
__global__ __launch_bounds__(256) void ln_k(
    float* __restrict__ s, const float* __restrict__ g,
    const float* __restrict__ b)
{
    const int row = blockIdx.x;
    const int tid = threadIdx.x;
    const size_t off = (size_t)row << 10;
    const float4 xv = ((const float4*)(s + off))[tid];
    float sum = xv.x + xv.y + xv.z + xv.w;
    float sq  = xv.x * xv.x + xv.y * xv.y + xv.z * xv.z + xv.w * xv.w;
#pragma unroll
    for (int o = 32; o > 0; o >>= 1) {
        sum += __shfl_down(sum, o, 64);
        sq  += __shfl_down(sq,  o, 64);
    }
    __shared__ float s1[4], s2[4];
    if ((tid & 63) == 0) { s1[tid >> 6] = sum; s2[tid >> 6] = sq; }
    __syncthreads();
    sum = s1[0] + s1[1] + s1[2] + s1[3];
    sq  = s2[0] + s2[1] + s2[2] + s2[3];
    const float mean = sum * (1.f / 1024.f);
    const float var  = sq * (1.f / 1024.f) - mean * mean;
    const float rstd = rsqrtf(var + 1e-5f);
    const float4 gv = ((const float4*)g)[tid];
    const float4 bv = ((const float4*)b)[tid];
    float4 y;
    y.x = (xv.x - mean) * rstd * gv.x + bv.x;
    y.y = (xv.y - mean) * rstd * gv.y + bv.y;
    y.z = (xv.z - mean) * rstd * gv.z + bv.z;
    y.w = (xv.w - mean) * rstd * gv.w + bv.w;
    ((float4*)(s + off))[tid] = y;
}

// ---------------------------------------------------------------------------
extern "C" void kernel_launch(void* const* d_in, const int* in_sizes, int n_in,
                              void* d_out, int out_size, void* d_ws, size_t ws_size,
                              hipStream_t stream)
{
    const float* x         = (const float*)d_in[0];   // (4,4096,1024)
    const float* hidden    = (const float*)d_in[1];   // (4,1,1024)
    const float* rnn_start = (const float*)d_in[2];   // (4,4096,1)
    const float* Win       = (const float*)d_in[3];   // (2,1024,1024)
    const float* bin_      = (const float*)d_in[4];   // (2,1024)
    const float* Wout      = (const float*)d_in[5];
    const float* bout      = (const float*)d_in[6];
    const float* W1        = (const float*)d_in[7];
    const float* b1        = (const float*)d_in[8];
    const float* W2        = (const float*)d_in[9];
    const float* b2        = (const float*)d_in[10];
    const float* ln_g      = (const float*)d_in[11];
    const float* ln_b      = (const float*)d_in[12];
    float* out = (float*)d_out;                // out(16777216 f32) ++ hidden_new(4096 f32)
    float* hT  = out + (1u << 24);

    // workspace layout
    char* p = (char*)d_ws;
    bf16* Wt    = (bf16*)p;                    p += 5ull * (1u << 20) * sizeof(bf16);
    bf16* slotA = (bf16*)p;                    p += (1ull << 24) * sizeof(bf16);  // xb, later hs
    bf16* slotB = (bf16*)p;                    p += (1ull << 24) * sizeof(bf16);  // v,  later outp
    bf16* slotC = (bf16*)p;                    p += (1ull << 24) * sizeof(bf16);  // f,  later x_
    float* Ac  = (float*)p;                    p += (1ull << 18) * sizeof(float);
    float* Bc  = (float*)p;                    p += (1ull << 18) * sizeof(float);
    float* Hin = (float*)p;                    p += (1ull << 18) * sizeof(float);

    bf16* WoutT = Wt + 2u * (1u << 20);
    bf16* W1T   = Wt + 3u * (1u << 20);
    bf16* W2T   = Wt + 4u * (1u << 20);

    convx_k<<<16384, 256, 0, stream>>>((const float4*)x, slotA);
    trc_k<<<dim3(32, 32, 5), 256, 0, stream>>>(Win, Win + (1u << 20), Wout, W1, W2, Wt);

    // merged dual GEMM: y>=4 -> Win1/sigmoid.  v -> slotB, f -> slotC
    gemmA_k<<<dim3(64, 8), 512, 0, stream>>>(slotA, Wt, bin_, rnn_start, nullptr,
                                             slotB, slotC, nullptr, 5);

    // chunked scan: hs -> slotA (xb dead), hT -> d_out tail
    scan1_k<<<1024, 256, 0, stream>>>(slotB, slotC, Ac, Bc);
    scanmid_k<<<16, 256, 0, stream>>>(Ac, Bc, hidden, Hin);
    scan2_k<<<1024, 256, 0, stream>>>(slotB, slotC, Hin, slotA, hT);

    // outp = hs@Wout + bout (-> slotB); x_ = gelu(outp@W1+b1) (-> slotC);
    // s = x_@W2 + b2 + outp -> f32 in d_out
    gemmA_k<<<dim3(64, 4), 512, 0, stream>>>(slotA, WoutT, bout, nullptr, nullptr,
                                             slotB, nullptr, nullptr, 2);
    gemmA_k<<<dim3(64, 4), 512, 0, stream>>>(slotB, W1T,   b1,   nullptr, nullptr,
                                             slotC, nullptr, nullptr, 3);
    gemmA_k<<<dim3(64, 4), 512, 0, stream>>>(slotC, W2T,   b2,   nullptr, slotB,
                                             nullptr, nullptr, out, 4);

    ln_k<<<16384, 256, 0, stream>>>(out, ln_g, ln_b);
}

// Round 7
// 479.655 us; speedup vs baseline: 1.3978x; 1.3883x over previous
//
#include <hip/hip_runtime.h>
#include <hip/hip_bf16.h>
#include <math.h>

typedef __hip_bfloat16 bf16;
typedef __bf16  bf16x8  __attribute__((ext_vector_type(8)));
typedef float   floatx4 __attribute__((ext_vector_type(4)));

typedef const __attribute__((address_space(1))) void global_cv_t;
typedef __attribute__((address_space(3))) void       lds_v_t;

static __device__ __forceinline__ float bf2f(bf16 h) { return __bfloat162float(h); }
static __device__ __forceinline__ bf16  f2bf(float f) { return __float2bfloat16(f); }

__device__ __forceinline__ void load_lds16(const void* g, void* l) {
    // async global->LDS, 16B per lane; LDS dest = wave-uniform base + lane*16
    __builtin_amdgcn_global_load_lds((global_cv_t*)g, (lds_v_t*)l, 16, 0, 0);
}

// ---------------------------------------------------------------------------
// x (f32, 16M elems) -> bf16, vectorized
// ---------------------------------------------------------------------------
__global__ __launch_bounds__(256) void convx_k(const float4* __restrict__ in,
                                               bf16* __restrict__ out)
{
    const int i = blockIdx.x * 256 + threadIdx.x;   // 0 .. 4194303
    const float4 v = in[i];
    bf16* o = out + (size_t)i * 4;
    o[0] = f2bf(v.x); o[1] = f2bf(v.y); o[2] = f2bf(v.z); o[3] = f2bf(v.w);
}

// ---------------------------------------------------------------------------
// Transpose+convert 5x (1024x1024 f32): dst[n][k] = (bf16)src[k][n]
// ---------------------------------------------------------------------------
__global__ __launch_bounds__(256) void trc_k(
    const float* __restrict__ w0, const float* __restrict__ w1,
    const float* __restrict__ w2, const float* __restrict__ w3,
    const float* __restrict__ w4, bf16* __restrict__ dst)
{
    const float* src;
    switch (blockIdx.z) {
        case 0: src = w0; break;
        case 1: src = w1; break;
        case 2: src = w2; break;
        case 3: src = w3; break;
        default: src = w4; break;
    }
    bf16* d = dst + ((size_t)blockIdx.z << 20);
    __shared__ float tile[32][33];
    const int tx = threadIdx.x & 31;
    const int ty = threadIdx.x >> 5;   // 0..7
    const int bx = blockIdx.x * 32, by = blockIdx.y * 32;
#pragma unroll
    for (int j = 0; j < 32; j += 8)
        tile[ty + j][tx] = src[(size_t)(by + ty + j) * 1024 + bx + tx];
    __syncthreads();
#pragma unroll
    for (int j = 0; j < 32; j += 8)
        d[(size_t)(bx + ty + j) * 1024 + by + tx] = f2bf(tile[tx][ty + j]);
}

// ---------------------------------------------------------------------------
// GEMM: C[m][n] = sum_k A[m][k] * Bt[n][k] + bias[n], mode-dependent epilogue.
// A, Bt bf16; bias f32. M=16384, N=1024, K=1024. 128x128 tile, BK=64, 4 waves.
//
// ROUND-7: this is the 418-us-proven r0 kernel (DMA staging, pre-swizzled
// global source, linear LDS dest, XOR-swizzled ds_read_b128 — 0 measured
// read conflicts, no spill) with ONE change: DOUBLE-BUFFERED staging with a
// single __syncthreads per K-step. r0 ran {barrier; stage; barrier} per step,
// draining the DMA right after issue -> full latency exposed each of 16
// steps. Now: {stage buf^1 for t+1} || {compute buf t} -> __syncthreads, so
// the DMA has the whole compute phase (~1500 cyc) to land before the drain.
// Correctness does NOT rest on vmcnt tricks: __syncthreads drains LDS-DMA on
// this toolchain (r0/r1-3 relied on it, all passed); buf^1's last readers
// finished before the previous barrier, so staging it this step is race-free.
// Cost: LDS 32->64 KiB -> 2 blocks/CU (launch_bounds(256,2): VGPR budget 256,
// no spill possible). Failed alternatives (256^2 8-phase, reg-staging):
// rounds 1-6, all slower than r0 — per-phase DMA drain / VGPR spill.
//
// LDS image: slot s (16B granule) of row r holds global granule s^(r&7);
// fragment read slot ((kk*4+quad)^(l16&7)) -> logical granule kk*4+quad.
//
// modes: 0=tanh->Db  1=sigmoid*(1-auxf[row])->Db  2=plain->Db  3=gelu->Db
//        4=(+auxb residual)->Df (f32)
//        5=dual: blockIdx.y selects {WinT0->tanh->Db, WinT1->sigmoid->Db2}
// ---------------------------------------------------------------------------
__global__ __launch_bounds__(256, 2) void gemmdb_k(
    const bf16* __restrict__ A, const bf16* __restrict__ Bt,
    const float* __restrict__ bias, const float* __restrict__ auxf,
    const bf16* __restrict__ auxb, bf16* __restrict__ Db,
    bf16* __restrict__ Db2, float* __restrict__ Df, const int mode)
{
    __shared__ alignas(16) bf16 As[2][128 * 64];   // 16 KiB each
    __shared__ alignas(16) bf16 Bs[2][128 * 64];   // total 64 KiB

    const int tid  = threadIdx.x;
    const int wave = tid >> 6;
    const int lane = tid & 63;
    const int quad = lane >> 4;
    const int l16  = lane & 15;
    const int sw   = l16 & 7;       // row-derived XOR key for fragment reads
    const int wm   = wave & 1;      // wave row (64 rows)
    const int wn   = wave >> 1;     // wave col (64 cols)
    const int bm   = blockIdx.x * 128;

    int bn, emode;
    const bf16* Bte = Bt;
    const float* biase = bias;
    bf16* Dbe = Db;
    if (mode == 5) {
        const int mat = blockIdx.y >> 3;          // 0: tanh/Win0, 1: sigmoid/Win1
        bn    = (blockIdx.y & 7) * 128;
        Bte   = Bt + ((size_t)mat << 20);
        biase = bias + (mat << 10);
        Dbe   = mat ? Db2 : Db;
        emode = mat ? 1 : 0;
    } else {
        bn = blockIdx.y * 128;
        emode = mode;
    }

    // staging (BK=64): chunk = 8 rows x 64 k = 1 KB. lane l -> row l>>3,
    // k-granule ((l&7) ^ (row&7))  [XOR swizzle via pre-swizzled global addr].
    const int srow  = lane >> 3;                       // 0..7 == row&7
    const int skoff = (((lane & 7) ^ srow) << 3);      // swizzled k elem-offset

    const bf16* gA = A   + (size_t)(bm + wave * 32 + srow) * 1024 + skoff;
    const bf16* gB = Bte + (size_t)(bn + wave * 32 + srow) * 1024 + skoff;

#define STAGE(BUF, KT) do {                                                       \
        _Pragma("unroll")                                                         \
        for (int c_ = 0; c_ < 4; ++c_) {                                          \
            load_lds16(gA + (size_t)c_ * 8192 + (KT) * 64,                        \
                       &As[BUF][wave * 2048 + c_ * 512]);                         \
            load_lds16(gB + (size_t)c_ * 8192 + (KT) * 64,                        \
                       &Bs[BUF][wave * 2048 + c_ * 512]);                         \
        }                                                                         \
    } while (0)

    floatx4 acc[4][4];
#pragma unroll
    for (int i = 0; i < 4; ++i)
#pragma unroll
        for (int j = 0; j < 4; ++j)
            acc[i][j] = (floatx4){0.f, 0.f, 0.f, 0.f};

#define COMPUTE(BUF) do {                                                         \
        _Pragma("unroll")                                                         \
        for (int kk_ = 0; kk_ < 2; ++kk_) {                                       \
            bf16x8 af_[4], bf_[4];                                                \
            _Pragma("unroll")                                                     \
            for (int t_ = 0; t_ < 4; ++t_) {                                      \
                const int g_ = ((kk_ * 4 + quad) ^ sw) << 3;                      \
                af_[t_] = *(const bf16x8*)&As[BUF][                               \
                    (wm * 64 + t_ * 16 + l16) * 64 + g_];                         \
                bf_[t_] = *(const bf16x8*)&Bs[BUF][                               \
                    (wn * 64 + t_ * 16 + l16) * 64 + g_];                         \
            }                                                                     \
            _Pragma("unroll")                                                     \
            for (int tm_ = 0; tm_ < 4; ++tm_)                                     \
                _Pragma("unroll")                                                 \
                for (int tn_ = 0; tn_ < 4; ++tn_)                                 \
                    acc[tm_][tn_] = __builtin_amdgcn_mfma_f32_16x16x32_bf16(      \
                        af_[tm_], bf_[tn_], acc[tm_][tn_], 0, 0, 0);              \
        }                                                                         \
    } while (0)

    // prologue: tile 0 -> buf0 (one-time latency exposure)
    STAGE(0, 0);
    __syncthreads();

#pragma unroll 1
    for (int it = 0; it < 8; ++it) {
        // kt = 2it: compute buf0, stage kt+1 -> buf1
        STAGE(1, 2 * it + 1);
        COMPUTE(0);
        __syncthreads();
        // kt = 2it+1: compute buf1, stage kt+2 -> buf0
        if (it < 7) STAGE(0, 2 * it + 2);
        COMPUTE(1);
        __syncthreads();
    }

#undef STAGE
#undef COMPUTE

    // epilogue. C/D layout: col = lane&15, row = quad*4 + reg (m89-verified)
    float bv[4];
#pragma unroll
    for (int tn = 0; tn < 4; ++tn)
        bv[tn] = biase[bn + wn * 64 + tn * 16 + l16];

#pragma unroll
    for (int tm = 0; tm < 4; ++tm) {
#pragma unroll
        for (int r = 0; r < 4; ++r) {
            const int gm = bm + wm * 64 + tm * 16 + quad * 4 + r;
            const size_t rowoff = (size_t)gm << 10;
            float rowmul = 1.f;
            if (emode == 1) rowmul = 1.f - auxf[gm];
#pragma unroll
            for (int tn = 0; tn < 4; ++tn) {
                const int gn = bn + wn * 64 + tn * 16 + l16;
                float val = acc[tm][tn][r] + bv[tn];
                if (emode == 0)      val = tanhf(val);
                else if (emode == 1) val = rowmul / (1.f + expf(-val));
                else if (emode == 3) val = 0.5f * val * (1.f + erff(val * 0.70710678118654752f));
                if (emode == 4) {
                    val += bf2f(auxb[rowoff + gn]);
                    Df[rowoff + gn] = val;
                } else {
                    Dbe[rowoff + gn] = f2bf(val);
                }
            }
        }
    }
}

// ---------------------------------------------------------------------------
// Chunked linear-recurrence scan: h[t] = f[t]*h[t-1] + (1-f[t])*v[t].
// T=4096 split into 64 chunks of 64. 4096 channels (b,d).
// ---------------------------------------------------------------------------
__global__ __launch_bounds__(256) void scan1_k(
    const bf16* __restrict__ v, const bf16* __restrict__ f,
    float* __restrict__ Ac, float* __restrict__ Bc)
{
    const int idx = blockIdx.x * 256 + threadIdx.x;   // 0..262143
    const int ch = idx & 4095;        // b*1024 + d
    const int c  = idx >> 12;         // chunk 0..63
    const int b  = ch >> 10, d = ch & 1023;
    const size_t base = ((size_t)(b * 4096 + c * 64) << 10) + d;
    float a = 1.f, hb = 0.f;
#pragma unroll 8
    for (int i = 0; i < 64; ++i) {
        const size_t o = base + ((size_t)i << 10);
        const float ft = bf2f(f[o]);
        const float vt = bf2f(v[o]);
        hb = fmaf(ft, hb, (1.f - ft) * vt);
        a *= ft;
    }
    Ac[c * 4096 + ch] = a;
    Bc[c * 4096 + ch] = hb;
}

__global__ __launch_bounds__(256) void scanmid_k(
    const float* __restrict__ Ac, const float* __restrict__ Bc,
    const float* __restrict__ hidden, float* __restrict__ Hin)
{
    const int ch = blockIdx.x * 256 + threadIdx.x;    // 0..4095
    float h = hidden[ch];
#pragma unroll 8
    for (int c = 0; c < 64; ++c) {
        Hin[c * 4096 + ch] = h;
        h = fmaf(Ac[c * 4096 + ch], h, Bc[c * 4096 + ch]);
    }
}

__global__ __launch_bounds__(256) void scan2_k(
    const bf16* __restrict__ v, const bf16* __restrict__ f,
    const float* __restrict__ Hin, bf16* __restrict__ hs,
    float* __restrict__ hT)
{
    const int idx = blockIdx.x * 256 + threadIdx.x;
    const int ch = idx & 4095;
    const int c  = idx >> 12;
    const int b  = ch >> 10, d = ch & 1023;
    const size_t base = ((size_t)(b * 4096 + c * 64) << 10) + d;
    float h = Hin[c * 4096 + ch];
#pragma unroll 8
    for (int i = 0; i < 64; ++i) {
        const size_t o = base + ((size_t)i << 10);
        const float ft = bf2f(f[o]);
        const float vt = bf2f(v[o]);
        h = fmaf(ft, h, (1.f - ft) * vt);
        hs[o] = f2bf(h);
    }
    if (c == 63) hT[ch] = h;
}

// ---------------------------------------------------------------------------
// LayerNorm over D=1024 (f32 in-place on d_out), one block per row.
// ---------------------------------------------------------------------------
__global__ __launch_bounds__(256) void ln_k(
    float* __restrict__ s, const float* __restrict__ g,
    const float* __restrict__ b)
{
    const int row = blockIdx.x;
    const int tid = threadIdx.x;
    const size_t off = (size_t)row << 10;
    const float4 xv = ((const float4*)(s + off))[tid];
    float sum = xv.x + xv.y + xv.z + xv.w;
    float sq  = xv.x * xv.x + xv.y * xv.y + xv.z * xv.z + xv.w * xv.w;
#pragma unroll
    for (int o = 32; o > 0; o >>= 1) {
        sum += __shfl_down(sum, o, 64);
        sq  += __shfl_down(sq,  o, 64);
    }
    __shared__ float s1[4], s2[4];
    if ((tid & 63) == 0) { s1[tid >> 6] = sum; s2[tid >> 6] = sq; }
    __syncthreads();
    sum = s1[0] + s1[1] + s1[2] + s1[3];
    sq  = s2[0] + s2[1] + s2[2] + s2[3];
    const float mean = sum * (1.f / 1024.f);
    const float var  = sq * (1.f / 1024.f) - mean * mean;
    const float rstd = rsqrtf(var + 1e-5f);
    const float4 gv = ((const float4*)g)[tid];
    const float4 bv = ((const float4*)b)[tid];
    float4 y;
    y.x = (xv.x - mean) * rstd * gv.x + bv.x;
    y.y = (xv.y - mean) * rstd * gv.y + bv.y;
    y.z = (xv.z - mean) * rstd * gv.z + bv.z;
    y.w = (xv.w - mean) * rstd * gv.w + bv.w;
    ((float4*)(s + off))[tid] = y;
}

// ---------------------------------------------------------------------------
extern "C" void kernel_launch(void* const* d_in, const int* in_sizes, int n_in,
                              void* d_out, int out_size, void* d_ws, size_t ws_size,
                              hipStream_t stream)
{
    const float* x         = (const float*)d_in[0];   // (4,4096,1024)
    const float* hidden    = (const float*)d_in[1];   // (4,1,1024)
    const float* rnn_start = (const float*)d_in[2];   // (4,4096,1)
    const float* Win       = (const float*)d_in[3];   // (2,1024,1024)
    const float* bin_      = (const float*)d_in[4];   // (2,1024)
    const float* Wout      = (const float*)d_in[5];
    const float* bout      = (const float*)d_in[6];
    const float* W1        = (const float*)d_in[7];
    const float* b1        = (const float*)d_in[8];
    const float* W2        = (const float*)d_in[9];
    const float* b2        = (const float*)d_in[10];
    const float* ln_g      = (const float*)d_in[11];
    const float* ln_b      = (const float*)d_in[12];
    float* out = (float*)d_out;                // out(16777216 f32) ++ hidden_new(4096 f32)
    float* hT  = out + (1u << 24);

    // workspace layout
    char* p = (char*)d_ws;
    bf16* Wt    = (bf16*)p;                    p += 5ull * (1u << 20) * sizeof(bf16);
    bf16* slotA = (bf16*)p;                    p += (1ull << 24) * sizeof(bf16);  // xb, later hs
    bf16* slotB = (bf16*)p;                    p += (1ull << 24) * sizeof(bf16);  // v,  later outp
    bf16* slotC = (bf16*)p;                    p += (1ull << 24) * sizeof(bf16);  // f,  later x_
    float* Ac  = (float*)p;                    p += (1ull << 18) * sizeof(float);
    float* Bc  = (float*)p;                    p += (1ull << 18) * sizeof(float);
    float* Hin = (float*)p;                    p += (1ull << 18) * sizeof(float);

    bf16* WoutT = Wt + 2u * (1u << 20);
    bf16* W1T   = Wt + 3u * (1u << 20);
    bf16* W2T   = Wt + 4u * (1u << 20);

    convx_k<<<16384, 256, 0, stream>>>((const float4*)x, slotA);
    trc_k<<<dim3(32, 32, 5), 256, 0, stream>>>(Win, Win + (1u << 20), Wout, W1, W2, Wt);

    // merged dual GEMM: y>=8 -> Win1/sigmoid.  v -> slotB, f -> slotC
    gemmdb_k<<<dim3(128, 16), 256, 0, stream>>>(slotA, Wt, bin_, rnn_start, nullptr,
                                                slotB, slotC, nullptr, 5);

    // chunked scan: hs -> slotA (xb dead), hT -> d_out tail
    scan1_k<<<1024, 256, 0, stream>>>(slotB, slotC, Ac, Bc);
    scanmid_k<<<16, 256, 0, stream>>>(Ac, Bc, hidden, Hin);
    scan2_k<<<1024, 256, 0, stream>>>(slotB, slotC, Hin, slotA, hT);

    // outp = hs@Wout + bout (-> slotB); x_ = gelu(outp@W1+b1) (-> slotC);
    // s = x_@W2 + b2 + outp -> f32 in d_out
    gemmdb_k<<<dim3(128, 8), 256, 0, stream>>>(slotA, WoutT, bout, nullptr, nullptr,
                                               slotB, nullptr, nullptr, 2);
    gemmdb_k<<<dim3(128, 8), 256, 0, stream>>>(slotB, W1T,   b1,   nullptr, nullptr,
                                               slotC, nullptr, nullptr, 3);
    gemmdb_k<<<dim3(128, 8), 256, 0, stream>>>(slotC, W2T,   b2,   nullptr, slotB,
                                               nullptr, nullptr, out, 4);

    ln_k<<<16384, 256, 0, stream>>>(out, ln_g, ln_b);
}

// Round 8
// 423.938 us; speedup vs baseline: 1.5815x; 1.1314x over previous
//
#include <hip/hip_runtime.h>
#include <hip/hip_bf16.h>
#include <math.h>

typedef __hip_bfloat16 bf16;
typedef __bf16  bf16x8  __attribute__((ext_vector_type(8)));
typedef float   floatx4 __attribute__((ext_vector_type(4)));

typedef const __attribute__((address_space(1))) void global_cv_t;
typedef __attribute__((address_space(3))) void       lds_v_t;

static __device__ __forceinline__ float bf2f(bf16 h) { return __bfloat162float(h); }
static __device__ __forceinline__ bf16  f2bf(float f) { return __float2bfloat16(f); }

__device__ __forceinline__ void load_lds16(const void* g, void* l) {
    // async global->LDS, 16B per lane; LDS dest = wave-uniform base + lane*16
    __builtin_amdgcn_global_load_lds((global_cv_t*)g, (lds_v_t*)l, 16, 0, 0);
}

// ---------------------------------------------------------------------------
// x (f32, 16M elems) -> bf16, vectorized
// ---------------------------------------------------------------------------
__global__ __launch_bounds__(256) void convx_k(const float4* __restrict__ in,
                                               bf16* __restrict__ out)
{
    const int i = blockIdx.x * 256 + threadIdx.x;   // 0 .. 4194303
    const float4 v = in[i];
    bf16* o = out + (size_t)i * 4;
    o[0] = f2bf(v.x); o[1] = f2bf(v.y); o[2] = f2bf(v.z); o[3] = f2bf(v.w);
}

// ---------------------------------------------------------------------------
// Transpose+convert 5x (1024x1024 f32): dst[n][k] = (bf16)src[k][n]
// ---------------------------------------------------------------------------
__global__ __launch_bounds__(256) void trc_k(
    const float* __restrict__ w0, const float* __restrict__ w1,
    const float* __restrict__ w2, const float* __restrict__ w3,
    const float* __restrict__ w4, bf16* __restrict__ dst)
{
    const float* src;
    switch (blockIdx.z) {
        case 0: src = w0; break;
        case 1: src = w1; break;
        case 2: src = w2; break;
        case 3: src = w3; break;
        default: src = w4; break;
    }
    bf16* d = dst + ((size_t)blockIdx.z << 20);
    __shared__ float tile[32][33];
    const int tx = threadIdx.x & 31;
    const int ty = threadIdx.x >> 5;   // 0..7
    const int bx = blockIdx.x * 32, by = blockIdx.y * 32;
#pragma unroll
    for (int j = 0; j < 32; j += 8)
        tile[ty + j][tx] = src[(size_t)(by + ty + j) * 1024 + bx + tx];
    __syncthreads();
#pragma unroll
    for (int j = 0; j < 32; j += 8)
        d[(size_t)(bx + ty + j) * 1024 + by + tx] = f2bf(tile[tx][ty + j]);
}

// ---------------------------------------------------------------------------
// GEMM: C[m][n] = sum_k A[m][k] * Bt[n][k] + bias[n], mode-dependent epilogue.
// A, Bt bf16; bias f32. M=16384, N=1024, K=1024. 128x128 tile, BK=64, 4 waves.
//
// ROUND-8: this is the 418-us r0 kernel RESTORED EXACTLY (single-buffer
// 32 KiB LDS, 4 blocks/CU — the only mechanism that hides the per-step DMA
// drain on this toolchain is cross-block TLP; rounds 1-7 proved dbuf /
// 8-phase / reg-staging all fail: the pre-barrier vmcnt(0) drains prefetches
// too). Two LOCAL additions that don't touch the loop structure:
//   1. XCD-chunked block swizzle (T1): linear dispatch strides same-A-panel
//      blocks 128 apart -> scattered over 8 XCDs -> A-panel DMA misses L2
//      (FETCH 82 MB >> A+B = 36 MB). Chunking puts each panel's consumers on
//      one XCD: the drained DMA becomes an own-L2 hit (~200 cyc vs 600-900).
//      nwg % 8 == 0 for all launches -> bijective.
//   2. Fast activations: tanh/sigmoid via __expf (v_exp_f32), replacing
//      branchy libm calls x 64 outputs/lane. Error ~1e-7 << bf16 quantum.
//      erff (gelu) kept exact.
//
// LDS image: slot s (16B granule) of row r holds global granule s^(r&7)
// (via pre-swizzled global source addr + linear DMA dest); fragment read
// slot ((kk*4+quad)^(l16&7)) -> 0 read bank conflicts (measured r1-3).
//
// modes: 0=tanh->Db  1=sigmoid*(1-auxf[row])->Db  2=plain->Db  3=gelu->Db
//        4=(+auxb residual)->Df (f32)
//        5=dual: ny selects {WinT0->tanh->Db, WinT1->sigmoid->Db2}
// ---------------------------------------------------------------------------
__global__ __launch_bounds__(256, 4) void gemm_k(
    const bf16* __restrict__ A, const bf16* __restrict__ Bt,
    const float* __restrict__ bias, const float* __restrict__ auxf,
    const bf16* __restrict__ auxb, bf16* __restrict__ Db,
    bf16* __restrict__ Db2, float* __restrict__ Df, const int mode)
{
    __shared__ alignas(16) bf16 As[128 * 64];
    __shared__ alignas(16) bf16 Bs[128 * 64];

    const int tid  = threadIdx.x;
    const int wave = tid >> 6;
    const int lane = tid & 63;
    const int quad = lane >> 4;
    const int l16  = lane & 15;
    const int sw   = l16 & 7;       // row-derived XOR key for fragment reads
    const int wm   = wave & 1;      // wave row (64 rows)
    const int wn   = wave >> 1;     // wave col (64 cols)

    // ---- XCD-chunked swizzle: consecutive remapped ids share an A-panel
    // and live on one XCD. nwg %% 8 == 0 (1024 or 2048). NBY in {8,16}.
    const int NBY  = gridDim.y;
    const int nwg  = gridDim.x * NBY;
    int bid = blockIdx.y * gridDim.x + blockIdx.x;     // HW linear (x fastest)
    bid = (bid & 7) * (nwg >> 3) + (bid >> 3);         // chunk per XCD
    const int nysh = (NBY == 16) ? 4 : 3;
    const int mi   = bid >> nysh;                      // A-panel index 0..127
    const int ny   = bid & (NBY - 1);                  // N/mat index
    const int bm   = mi * 128;

    int bn, emode;
    const bf16* Bte = Bt;
    const float* biase = bias;
    bf16* Dbe = Db;
    if (mode == 5) {
        const int mat = ny >> 3;                  // 0: tanh/Win0, 1: sigmoid/Win1
        bn    = (ny & 7) * 128;
        Bte   = Bt + ((size_t)mat << 20);
        biase = bias + (mat << 10);
        Dbe   = mat ? Db2 : Db;
        emode = mat ? 1 : 0;
    } else {
        bn = ny * 128;
        emode = mode;
    }

    // staging (BK=64): chunk = 8 rows x 64 k = 1 KB. lane l -> row l>>3,
    // k-granule ((l&7) ^ (row&7))  [XOR swizzle via pre-swizzled global addr].
    const int srow  = lane >> 3;                       // 0..7 == row&7
    const int skoff = (((lane & 7) ^ srow) << 3);      // swizzled k elem-offset

    const bf16* gA = A   + (size_t)(bm + wave * 32 + srow) * 1024 + skoff;
    const bf16* gB = Bte + (size_t)(bn + wave * 32 + srow) * 1024 + skoff;
    bf16* lA = &As[wave * 2048];
    bf16* lB = &Bs[wave * 2048];

    floatx4 acc[4][4];
#pragma unroll
    for (int i = 0; i < 4; ++i)
#pragma unroll
        for (int j = 0; j < 4; ++j)
            acc[i][j] = (floatx4){0.f, 0.f, 0.f, 0.f};

    for (int k0 = 0; k0 < 1024; k0 += 64) {
        __syncthreads();
#pragma unroll
        for (int c = 0; c < 4; ++c) {
            load_lds16(gA + (size_t)c * 8192 + k0, lA + c * 512);
            load_lds16(gB + (size_t)c * 8192 + k0, lB + c * 512);
        }
        __syncthreads();   // vmcnt(0) drain before barrier

#pragma unroll
        for (int kk = 0; kk < 2; ++kk) {
            bf16x8 af[4], bfr[4];
#pragma unroll
            for (int t = 0; t < 4; ++t) {
                const int g = ((kk * 4 + quad) ^ sw) << 3;   // swizzled granule
                af[t]  = *(const bf16x8*)&As[(wm * 64 + t * 16 + l16) * 64 + g];
                bfr[t] = *(const bf16x8*)&Bs[(wn * 64 + t * 16 + l16) * 64 + g];
            }
#pragma unroll
            for (int tm = 0; tm < 4; ++tm)
#pragma unroll
                for (int tn = 0; tn < 4; ++tn)
                    acc[tm][tn] = __builtin_amdgcn_mfma_f32_16x16x32_bf16(
                        af[tm], bfr[tn], acc[tm][tn], 0, 0, 0);
        }
    }

    // epilogue. C/D layout: col = lane&15, row = quad*4 + reg (m89-verified)
    float bv[4];
#pragma unroll
    for (int tn = 0; tn < 4; ++tn)
        bv[tn] = biase[bn + wn * 64 + tn * 16 + l16];

#pragma unroll
    for (int tm = 0; tm < 4; ++tm) {
#pragma unroll
        for (int r = 0; r < 4; ++r) {
            const int gm = bm + wm * 64 + tm * 16 + quad * 4 + r;
            const size_t rowoff = (size_t)gm << 10;
            float rowmul = 1.f;
            if (emode == 1) rowmul = 1.f - auxf[gm];
#pragma unroll
            for (int tn = 0; tn < 4; ++tn) {
                const int gn = bn + wn * 64 + tn * 16 + l16;
                float val = acc[tm][tn][r] + bv[tn];
                if (emode == 0)      val = 1.f - 2.f / (1.f + __expf(2.f * val));
                else if (emode == 1) val = rowmul / (1.f + __expf(-val));
                else if (emode == 3) val = 0.5f * val * (1.f + erff(val * 0.70710678118654752f));
                if (emode == 4) {
                    val += bf2f(auxb[rowoff + gn]);
                    Df[rowoff + gn] = val;
                } else {
                    Dbe[rowoff + gn] = f2bf(val);
                }
            }
        }
    }
}

// ---------------------------------------------------------------------------
// Chunked linear-recurrence scan: h[t] = f[t]*h[t-1] + (1-f[t])*v[t].
// T=4096 split into 64 chunks of 64. 4096 channels (b,d).
// ---------------------------------------------------------------------------
__global__ __launch_bounds__(256) void scan1_k(
    const bf16* __restrict__ v, const bf16* __restrict__ f,
    float* __restrict__ Ac, float* __restrict__ Bc)
{
    const int idx = blockIdx.x * 256 + threadIdx.x;   // 0..262143
    const int ch = idx & 4095;        // b*1024 + d
    const int c  = idx >> 12;         // chunk 0..63
    const int b  = ch >> 10, d = ch & 1023;
    const size_t base = ((size_t)(b * 4096 + c * 64) << 10) + d;
    float a = 1.f, hb = 0.f;
#pragma unroll 8
    for (int i = 0; i < 64; ++i) {
        const size_t o = base + ((size_t)i << 10);
        const float ft = bf2f(f[o]);
        const float vt = bf2f(v[o]);
        hb = fmaf(ft, hb, (1.f - ft) * vt);
        a *= ft;
    }
    Ac[c * 4096 + ch] = a;
    Bc[c * 4096 + ch] = hb;
}

__global__ __launch_bounds__(256) void scanmid_k(
    const float* __restrict__ Ac, const float* __restrict__ Bc,
    const float* __restrict__ hidden, float* __restrict__ Hin)
{
    const int ch = blockIdx.x * 256 + threadIdx.x;    // 0..4095
    float h = hidden[ch];
#pragma unroll 8
    for (int c = 0; c < 64; ++c) {
        Hin[c * 4096 + ch] = h;
        h = fmaf(Ac[c * 4096 + ch], h, Bc[c * 4096 + ch]);
    }
}

__global__ __launch_bounds__(256) void scan2_k(
    const bf16* __restrict__ v, const bf16* __restrict__ f,
    const float* __restrict__ Hin, bf16* __restrict__ hs,
    float* __restrict__ hT)
{
    const int idx = blockIdx.x * 256 + threadIdx.x;
    const int ch = idx & 4095;
    const int c  = idx >> 12;
    const int b  = ch >> 10, d = ch & 1023;
    const size_t base = ((size_t)(b * 4096 + c * 64) << 10) + d;
    float h = Hin[c * 4096 + ch];
#pragma unroll 8
    for (int i = 0; i < 64; ++i) {
        const size_t o = base + ((size_t)i << 10);
        const float ft = bf2f(f[o]);
        const float vt = bf2f(v[o]);
        h = fmaf(ft, h, (1.f - ft) * vt);
        hs[o] = f2bf(h);
    }
    if (c == 63) hT[ch] = h;
}

// ---------------------------------------------------------------------------
// LayerNorm over D=1024 (f32 in-place on d_out), one block per row.
// ---------------------------------------------------------------------------
__global__ __launch_bounds__(256) void ln_k(
    float* __restrict__ s, const float* __restrict__ g,
    const float* __restrict__ b)
{
    const int row = blockIdx.x;
    const int tid = threadIdx.x;
    const size_t off = (size_t)row << 10;
    const float4 xv = ((const float4*)(s + off))[tid];
    float sum = xv.x + xv.y + xv.z + xv.w;
    float sq  = xv.x * xv.x + xv.y * xv.y + xv.z * xv.z + xv.w * xv.w;
#pragma unroll
    for (int o = 32; o > 0; o >>= 1) {
        sum += __shfl_down(sum, o, 64);
        sq  += __shfl_down(sq,  o, 64);
    }
    __shared__ float s1[4], s2[4];
    if ((tid & 63) == 0) { s1[tid >> 6] = sum; s2[tid >> 6] = sq; }
    __syncthreads();
    sum = s1[0] + s1[1] + s1[2] + s1[3];
    sq  = s2[0] + s2[1] + s2[2] + s2[3];
    const float mean = sum * (1.f / 1024.f);
    const float var  = sq * (1.f / 1024.f) - mean * mean;
    const float rstd = rsqrtf(var + 1e-5f);
    const float4 gv = ((const float4*)g)[tid];
    const float4 bv = ((const float4*)b)[tid];
    float4 y;
    y.x = (xv.x - mean) * rstd * gv.x + bv.x;
    y.y = (xv.y - mean) * rstd * gv.y + bv.y;
    y.z = (xv.z - mean) * rstd * gv.z + bv.z;
    y.w = (xv.w - mean) * rstd * gv.w + bv.w;
    ((float4*)(s + off))[tid] = y;
}

// ---------------------------------------------------------------------------
extern "C" void kernel_launch(void* const* d_in, const int* in_sizes, int n_in,
                              void* d_out, int out_size, void* d_ws, size_t ws_size,
                              hipStream_t stream)
{
    const float* x         = (const float*)d_in[0];   // (4,4096,1024)
    const float* hidden    = (const float*)d_in[1];   // (4,1,1024)
    const float* rnn_start = (const float*)d_in[2];   // (4,4096,1)
    const float* Win       = (const float*)d_in[3];   // (2,1024,1024)
    const float* bin_      = (const float*)d_in[4];   // (2,1024)
    const float* Wout      = (const float*)d_in[5];
    const float* bout      = (const float*)d_in[6];
    const float* W1        = (const float*)d_in[7];
    const float* b1        = (const float*)d_in[8];
    const float* W2        = (const float*)d_in[9];
    const float* b2        = (const float*)d_in[10];
    const float* ln_g      = (const float*)d_in[11];
    const float* ln_b      = (const float*)d_in[12];
    float* out = (float*)d_out;                // out(16777216 f32) ++ hidden_new(4096 f32)
    float* hT  = out + (1u << 24);

    // workspace layout
    char* p = (char*)d_ws;
    bf16* Wt    = (bf16*)p;                    p += 5ull * (1u << 20) * sizeof(bf16);
    bf16* slotA = (bf16*)p;                    p += (1ull << 24) * sizeof(bf16);  // xb, later hs
    bf16* slotB = (bf16*)p;                    p += (1ull << 24) * sizeof(bf16);  // v,  later outp
    bf16* slotC = (bf16*)p;                    p += (1ull << 24) * sizeof(bf16);  // f,  later x_
    float* Ac  = (float*)p;                    p += (1ull << 18) * sizeof(float);
    float* Bc  = (float*)p;                    p += (1ull << 18) * sizeof(float);
    float* Hin = (float*)p;                    p += (1ull << 18) * sizeof(float);

    bf16* WoutT = Wt + 2u * (1u << 20);
    bf16* W1T   = Wt + 3u * (1u << 20);
    bf16* W2T   = Wt + 4u * (1u << 20);

    convx_k<<<16384, 256, 0, stream>>>((const float4*)x, slotA);
    trc_k<<<dim3(32, 32, 5), 256, 0, stream>>>(Win, Win + (1u << 20), Wout, W1, W2, Wt);

    // merged dual GEMM: ny>=8 -> Win1/sigmoid.  v -> slotB, f -> slotC
    gemm_k<<<dim3(128, 16), 256, 0, stream>>>(slotA, Wt, bin_, rnn_start, nullptr,
                                              slotB, slotC, nullptr, 5);

    // chunked scan: hs -> slotA (xb dead), hT -> d_out tail
    scan1_k<<<1024, 256, 0, stream>>>(slotB, slotC, Ac, Bc);
    scanmid_k<<<16, 256, 0, stream>>>(Ac, Bc, hidden, Hin);
    scan2_k<<<1024, 256, 0, stream>>>(slotB, slotC, Hin, slotA, hT);

    // outp = hs@Wout + bout (-> slotB); x_ = gelu(outp@W1+b1) (-> slotC);
    // s = x_@W2 + b2 + outp -> f32 in d_out
    gemm_k<<<dim3(128, 8), 256, 0, stream>>>(slotA, WoutT, bout, nullptr, nullptr,
                                             slotB, nullptr, nullptr, 2);
    gemm_k<<<dim3(128, 8), 256, 0, stream>>>(slotB, W1T,   b1,   nullptr, nullptr,
                                             slotC, nullptr, nullptr, 3);
    gemm_k<<<dim3(128, 8), 256, 0, stream>>>(slotC, W2T,   b2,   nullptr, slotB,
                                             nullptr, nullptr, out, 4);

    ln_k<<<16384, 256, 0, stream>>>(out, ln_g, ln_b);
}